// Round 1
// baseline (84.599 us; speedup 1.0000x reference)
//
#include <hip/hip_runtime.h>

// Guitar string (Karplus-Strong waveguide), MI355X gfx950.
//
// LTI reformulation (validated rounds 2-6): A (l->r, 2 taps) and B (r->l,
// 4 taps) commute; both parities evolve by C = A*B (5 taps, lag QB=DU+DD+2).
// Evolve y_m = (C^8)^m (0.5 e) (33 taps, lag 8QB); E14 = sum_{0..14} y_m;
//   E61 = (1+C^2)(1+C^4) E14 + (1+C^2) y15,  z62 = C^4 y15,
//   U = (1+C) E61 + z62,  ls = (1+B)U + C z62,  rs = (1+A)U + C z62.
//
// Round 8: the r7 "fix" did not take — rocprof still shows VGPR_Count=64
// (launch_bounds' 2nd arg is only a MIN waves/EU; the allocator targeted
// 8/EU = 64 regs anyway, serializing/spilling the ~100-float evolve live
// set -> ~47% VALUBusy). Now pin amdgpu_waves_per_eu(4,4) (LDS already
// caps at 1 block = 4 waves/EU, so max=4 costs nothing) for a hard 128-reg
// budget; split all tap convolutions into 2 partial chains (tapsum<NT>);
// preload pass-1's sg into registers right after the first barrier (T14 —
// fetch overlaps evolve step 0; P0's serial global phase disappears),
// trimmed to the epilogue's actual reach (s4 >= 7*E8 - 512, chunk != 0).
// Staging loads moved ahead of the ~450-instr tap build to hide latency.
//
// Geometry: 64 rows x 4 chunks of 8000. SPAN=16384, HALO=8384 >= 8*E8
// (E8=8QB<=1048; QB<=131 since nUp+nDn=128). Pass1: F0=7*E8<=7336; epilogue
// worst-case reach 63*QB+DD+13 = 8382 <= 8384. PADF=1056 >= E8.

#define TLEN   32000
#define NROW   64
#define CHUNK  8000
#define NTH    1024
#define PT     16
#define PT4    (PT/4)
#define SPAN   (NTH*PT)        // 16384
#define HALO   (SPAN-CHUNK)    // 8384
#define PADF   1056            // front zero pad >= E8 max (1048)
#define BUF    (PADF+SPAN)     // 17440 floats = 69.76 KB per buffer

__device__ inline int swz4(int f) {        // f: float index, multiple of 4
  int B = f >> 2;
  B ^= (B >> 3) & 7;                       // permute 16B blocks in 8-groups
  return B << 2;
}

__device__ inline float sgprf(float x) {
  return __uint_as_float(__builtin_amdgcn_readfirstlane(__float_as_uint(x)));
}

// Dot product with 2 independent accumulator chains (latency-robust even
// when few waves are alive on a SIMD; also a hint to the allocator that
// m-major serialization is not required).
template<int NT>
__device__ inline float tapsum(const float* W, const float* v) {
  float s0 = W[0] * v[0];
  float s1 = (NT > 1) ? W[1] * v[1] : 0.0f;
#pragma unroll
  for (int m = 2; m + 1 < NT; m += 2) {
    s0 = fmaf(W[m],     v[m],     s0);
    s1 = fmaf(W[m + 1], v[m + 1], s1);
  }
  if (NT > 2 && (NT & 1)) s0 = fmaf(W[NT - 1], v[NT - 1], s0);
  return s0 + s1;
}

struct Cf { int DU, DD, QB; float a[2], b[4], q[5], q2[9], q4[17], q8[33]; };

__device__ inline void build_from(float Lf, float pv, Cf& c) {
  const float p   = 0.1f + 0.8f * pv;
  const float nUp = Lf * p;
  const float nDn = Lf * (1.0f - p);
  c.DU = (int)ceilf(nUp);
  c.DD = (int)ceilf(nDn);
  const float fU = (float)c.DU - nUp;
  const float fD = (float)c.DD - nDn;
  const float GN  = -0.99f * 0.999f;        // NUT * VIB
  const float GB2 = -0.99f * 0.999f * 0.5f; // BRIDGE * VIB * 0.5
  c.a[0] = GN * (1.0f - fU);                // A: lag DU - i
  c.a[1] = GN * fU;
  const float w0 = 1.0f - fD, w1 = fD;
  c.b[0] = GB2 * (0.3f * w0);               // B: lag DD+2 - i
  c.b[1] = GB2 * (w0 + 0.3f * w1);
  c.b[2] = GB2 * (0.7f * w0 + w1);
  c.b[3] = GB2 * (0.7f * w1);
  c.QB = c.DU + c.DD + 2;                   // C: lag QB - i
#pragma unroll
  for (int m = 0; m < 5; ++m) c.q[m] = 0.f;
#pragma unroll
  for (int i = 0; i < 2; ++i)
#pragma unroll
    for (int j = 0; j < 4; ++j) c.q[i+j] = fmaf(c.a[i], c.b[j], c.q[i+j]);
#pragma unroll
  for (int m = 0; m < 9; ++m) c.q2[m] = 0.f;
#pragma unroll
  for (int i = 0; i < 5; ++i)
#pragma unroll
    for (int j = 0; j < 5; ++j) c.q2[i+j] = fmaf(c.q[i], c.q[j], c.q2[i+j]);
#pragma unroll
  for (int m = 0; m < 17; ++m) c.q4[m] = 0.f;
#pragma unroll
  for (int i = 0; i < 9; ++i)
#pragma unroll
    for (int j = 0; j < 9; ++j) c.q4[i+j] = fmaf(c.q2[i], c.q2[j], c.q4[i+j]);
#pragma unroll
  for (int m = 0; m < 33; ++m) c.q8[m] = 0.f;
#pragma unroll
  for (int i = 0; i < 17; ++i)
#pragma unroll
    for (int j = 0; j < 17; ++j) c.q8[i+j] = fmaf(c.q4[i], c.q4[j], c.q8[i+j]);
}

template<int NF4>
__device__ inline void ldwin(const float* b, int basef, float* v) {
#pragma unroll
  for (int i = 0; i < NF4; ++i) {
    float4 t4 = *(const float4*)&b[swz4(basef + 4*i)];
    v[4*i+0] = t4.x; v[4*i+1] = t4.y; v[4*i+2] = t4.z; v[4*i+3] = t4.w;
  }
}

__device__ inline void stown(float* b, const int* wro, const float* v) {
#pragma unroll
  for (int k = 0; k < PT4; ++k)
    *(float4*)&b[wro[k]] = make_float4(v[4*k], v[4*k+1], v[4*k+2], v[4*k+3]);
}

__global__
__attribute__((amdgpu_flat_work_group_size(NTH, NTH), amdgpu_waves_per_eu(4, 4)))
void gs_pass(const int* __restrict__ lenp, const float* __restrict__ pp,
             const float* __restrict__ exc,
             float* __restrict__ zg, float* __restrict__ sg,
             float* __restrict__ lout, float* __restrict__ rout, int pass)
{
  __shared__ __align__(16) float bufA[BUF];
  __shared__ __align__(16) float bufB[BUF];

  const int row   = blockIdx.x >> 2;
  const int chunk = blockIdx.x & 3;
  const int t0    = chunk * CHUNK;
  const int tid   = threadIdx.x;
  const int sbase = tid * PT;
  const size_t rb = (size_t)row * TLEN;
  const int steps = pass ? 7 : 8;

  // ---- staging first: global loads issue before the ~450-instr tap build,
  //      so DRAM latency hides under VALU work ----
  const float4 f4z = make_float4(0.f, 0.f, 0.f, 0.f);
  if (tid * 4 < PADF) {                                // zero front pads
    *(float4*)&bufA[swz4(tid*4)] = f4z;
    *(float4*)&bufB[swz4(tid*4)] = f4z;
  }
  if (chunk == 0) {                                    // true zeros at t<0
    for (int s4 = tid*4; s4 < HALO; s4 += NTH*4)
      *(float4*)&bufB[swz4(PADF + s4)] = f4z;
  }
#pragma unroll
  for (int k = 0; k < 4; ++k) {                        // coalesced state load
    int s4 = tid*4 + k*(NTH*4);
    int t  = t0 - HALO + s4;
    float4 v = f4z;
    if (t >= 0) {
      if (pass == 0) {
        float4 e = *(const float4*)&exc[rb + t];
        v = make_float4(0.5f*e.x, 0.5f*e.y, 0.5f*e.z, 0.5f*e.w);
      } else {
        v = *(const float4*)&zg[rb + t];
      }
    }
    *(float4*)&bufA[swz4(PADF + s4)] = v;
  }

  // ---- taps for the evolve loop (W in SGPRs; only E8 else stays live) ----
  int E8;
  float W[33];
  {
    Cf c0; build_from((float)lenp[0], pp[0], c0);
#pragma unroll
    for (int m = 0; m < 33; ++m) W[m] = sgprf(c0.q8[m]);
    E8 = 8 * c0.QB;                       // multiple of 8, <= 1048
  }

  // ---- precomputed swizzled offsets ----
  int rdo[12], wro[PT4];
#pragma unroll
  for (int i = 0; i < 12; ++i) rdo[i] = swz4(PADF + sbase - E8 + 4*i);
#pragma unroll
  for (int k = 0; k < PT4; ++k) wro[k] = swz4(PADF + sbase + 4*k);

  __syncthreads();

  // ---- pass-1: preload sg into registers (T14 async-stage). Issued here so
  // the fetch overlaps evolve step 0; consumed only at P0 after 7 steps.
  // Trim to the epilogue's reach: E14 is read down to ~F0-280 (chunk != 0).
  const int F0v = 7 * E8;
  float4 sgr[4] = {f4z, f4z, f4z, f4z};
  if (pass) {
#pragma unroll
    for (int k = 0; k < 4; ++k) {
      int s4 = tid*4 + k*(NTH*4);
      int t  = t0 - HALO + s4;
      if (t >= 0 && (chunk == 0 || s4 >= F0v - 512))
        sgr[k] = *(const float4*)&sg[rb + t];
    }
  }

  float* cur = bufA;
  float* nxt = bufB;

  // own samples + partial sum
  float z[PT], acc[PT];
#pragma unroll
  for (int k = 0; k < PT4; ++k) {
    float4 t4 = *(const float4*)&cur[wro[k]];
    z[4*k+0] = t4.x; z[4*k+1] = t4.y; z[4*k+2] = t4.z; z[4*k+3] = t4.w;
  }
#pragma unroll
  for (int j = 0; j < PT; ++j) acc[j] = 0.f;

  // ---- evolve (z updated in place; acc += old z first) ----
  for (int s = 0; s < steps; ++s) {
    const int limit = (chunk == 0) ? HALO : (s + 1) * E8;
    const bool alive = (sbase + PT > limit);
    if (alive) {
      float v[48];                         // PT + 32 floats, 16B-aligned
#pragma unroll
      for (int i = 0; i < 12; ++i) {
        float4 t4 = *(const float4*)&cur[rdo[i]];
        v[4*i+0] = t4.x; v[4*i+1] = t4.y; v[4*i+2] = t4.z; v[4*i+3] = t4.w;
      }
#pragma unroll
      for (int j = 0; j < PT; ++j) acc[j] += z[j];
#pragma unroll
      for (int j = 0; j < PT; ++j) z[j] = tapsum<33>(W, v + j);
      stown(nxt, wro, z);
    }
    __syncthreads();
    float* tp = cur; cur = nxt; nxt = tp;
  }

  if (pass == 0) {
    // cur = y8, stage acc; writeback own region.
    stown(nxt, wro, acc);
    __syncthreads();
#pragma unroll
    for (int k = 0; k < 2; ++k) {
      int s4 = HALO + tid*4 + k*(NTH*4);
      if (s4 < SPAN) {
        int t = t0 + s4 - HALO;
        *(float4*)&zg[rb + t] = *(const float4*)&cur[swz4(PADF + s4)];
        *(float4*)&sg[rb + t] = *(const float4*)&nxt[swz4(PADF + s4)];
      }
    }
    return;
  }

  // ================= pass 1 epilogue (cur = y15, z = y15 own) ===========
  // P0: E14 = acc + sg (preloaded in sgr) into nxt — pure LDS RMW now.
  stown(nxt, wro, acc);
  __syncthreads();
#pragma unroll
  for (int k = 0; k < 4; ++k) {
    int s4 = tid*4 + k*(NTH*4);
    int o = swz4(PADF + s4);
    float4 a4 = *(const float4*)&nxt[o];
    *(float4*)&nxt[o] = make_float4(a4.x + sgr[k].x, a4.y + sgr[k].y,
                                    a4.z + sgr[k].z, a4.w + sgr[k].w);
  }
  __syncthreads();

  // Rebuild taps (volatile re-reads keep the evolve loop lean); SGPR-hoist.
  Cf c;
  {
    volatile const int* vl = lenp;
    volatile const float* vp = pp;
    build_from((float)vl[0], vp[0], c);
  }
  const int L2 = 2*c.QB, L4 = 4*c.QB, LQ = c.QB, LB = c.DD + 2, LA = c.DU;
  const int L2e = (L2+3)&~3, sh2 = L2e-L2;
  const int LQe = (LQ+3)&~3, shq = LQe-LQ;
  const int LBe = (LB+3)&~3, shb = LBe-LB;
  const int LAe = (LA+3)&~3, sha = LAe-LA;
  float q4f[17], T2[12], TQ[8], TB[7], TA[5];
#pragma unroll
  for (int i = 0; i < 17; ++i) q4f[i] = sgprf(c.q4[i]);
#pragma unroll
  for (int m = 0; m < 12; ++m) {
    float v = 0.f;
#pragma unroll
    for (int i = 0; i < 9; ++i) if (m == sh2 + i) v = c.q2[i];
    T2[m] = sgprf(v);
  }
#pragma unroll
  for (int m = 0; m < 8; ++m) {
    float v = 0.f;
#pragma unroll
    for (int i = 0; i < 5; ++i) if (m == shq + i) v = c.q[i];
    TQ[m] = sgprf(v);
  }
#pragma unroll
  for (int m = 0; m < 7; ++m) {
    float v = 0.f;
#pragma unroll
    for (int i = 0; i < 4; ++i) if (m == shb + i) v = c.b[i];
    TB[m] = sgprf(v);
  }
#pragma unroll
  for (int m = 0; m < 5; ++m) {
    float v = 0.f;
#pragma unroll
    for (int i = 0; i < 2; ++i) if (m == sha + i) v = c.a[i];
    TA[m] = sgprf(v);
  }

  const int  F0 = F0v;
  const bool ae = (chunk == 0) || (sbase + PT > F0);

  // Ph-A: H1 = (1+C^2)E14 ; Y2 = (1+C^2)y15 ; z62 = C^4 y15
  float H1[PT], Y2[PT], z62[PT];
  if (ae) {
    float e0[PT];
#pragma unroll
    for (int k = 0; k < PT4; ++k) {
      float4 t4 = *(const float4*)&nxt[wro[k]];
      e0[4*k+0] = t4.x; e0[4*k+1] = t4.y; e0[4*k+2] = t4.z; e0[4*k+3] = t4.w;
    }
    float w[28];
    ldwin<7>(nxt, PADF + sbase - L2e, w);
#pragma unroll
    for (int j = 0; j < PT; ++j) H1[j] = e0[j] + tapsum<12>(T2, w + j);
    ldwin<7>(cur, PADF + sbase - L2e, w);
#pragma unroll
    for (int j = 0; j < PT; ++j) Y2[j] = z[j] + tapsum<12>(T2, w + j);
    float w4[32];
    ldwin<8>(cur, PADF + sbase - L4, w4);    // L4 = 4QB, multiple of 4
#pragma unroll
    for (int j = 0; j < PT; ++j) z62[j] = tapsum<17>(q4f, w4 + j);
  }
  __syncthreads();
  if (ae) { stown(nxt, wro, H1); stown(cur, wro, z62); }
  __syncthreads();

  // Ph-B: E61 = H1 + C^4 H1 + Y2
  float E61[PT];
  if (ae) {
    float w4[32];
    ldwin<8>(nxt, PADF + sbase - L4, w4);
#pragma unroll
    for (int j = 0; j < PT; ++j)
      E61[j] = H1[j] + Y2[j] + tapsum<17>(q4f, w4 + j);
  }
  __syncthreads();
  if (ae) stown(nxt, wro, E61);
  __syncthreads();

  // Ph-C: U = E61 + C E61 + z62 ; V = C z62
  float U[PT], V[PT];
  if (ae) {
    float w[24];
    ldwin<6>(nxt, PADF + sbase - LQe, w);
#pragma unroll
    for (int j = 0; j < PT; ++j) U[j] = E61[j] + z62[j] + tapsum<8>(TQ, w + j);
    ldwin<6>(cur, PADF + sbase - LQe, w);
#pragma unroll
    for (int j = 0; j < PT; ++j) V[j] = tapsum<8>(TQ, w + j);
  }
  __syncthreads();
  if (ae) stown(nxt, wro, U);
  __syncthreads();

  // Ph-D: s0 = U+V (into V); ls = s0 + B U; rs = s0 + A U
  float LSv[PT], RSv[PT];
  if (ae) {
#pragma unroll
    for (int j = 0; j < PT; ++j) V[j] += U[j];
    {
      float wb[24];
      ldwin<6>(nxt, PADF + sbase - LBe, wb);
#pragma unroll
      for (int j = 0; j < PT; ++j) LSv[j] = V[j] + tapsum<7>(TB, wb + j);
    }
    {
      float wa[20];
      ldwin<5>(nxt, PADF + sbase - LAe, wa);
#pragma unroll
      for (int j = 0; j < PT; ++j) RSv[j] = V[j] + tapsum<5>(TA, wa + j);
    }
  }
  __syncthreads();
  if (ae) { stown(cur, wro, LSv); stown(nxt, wro, RSv); }
  __syncthreads();

  // coalesced output store
#pragma unroll
  for (int k = 0; k < 2; ++k) {
    int s4 = HALO + tid*4 + k*(NTH*4);
    if (s4 < SPAN) {
      int t = t0 + s4 - HALO;
      *(float4*)&lout[rb + t] = *(const float4*)&cur[swz4(PADF + s4)];
      *(float4*)&rout[rb + t] = *(const float4*)&nxt[swz4(PADF + s4)];
    }
  }
}

extern "C" void kernel_launch(void* const* d_in, const int* in_sizes, int n_in,
                              void* d_out, int out_size, void* d_ws, size_t ws_size,
                              hipStream_t stream) {
  (void)in_sizes; (void)n_in; (void)out_size; (void)ws_size;

  const int*   lenp = (const int*)d_in[0];
  const float* pp   = (const float*)d_in[1];
  const float* exc  = (const float*)d_in[2];

  float* lout = (float*)d_out;                  // ls: 64*32000 f32
  float* rout = lout + (size_t)NROW * TLEN;     // rs

  float* zg = (float*)d_ws;                     // state y8
  float* sg = zg + (size_t)NROW * TLEN;         // partial sum y0..y7

  dim3 grid(NROW * 4);
  gs_pass<<<grid, dim3(NTH), 0, stream>>>(lenp, pp, exc, zg, sg, lout, rout, 0);
  gs_pass<<<grid, dim3(NTH), 0, stream>>>(lenp, pp, exc, zg, sg, lout, rout, 1);
}

// Round 2
// 82.077 us; speedup vs baseline: 1.0307x; 1.0307x over previous
//
#include <hip/hip_runtime.h>

// Guitar string (Karplus-Strong waveguide), MI355X gfx950.
//
// LTI reformulation (validated rounds 2-6): A (l->r, 2 taps) and B (r->l,
// 4 taps) commute; both parities evolve by C = A*B (5 taps, lag QB=DU+DD+2).
// Evolve y_m = (C^8)^m (0.5 e) (33 taps, lag 8QB); E14 = sum_{0..14} y_m;
//   E61 = (1+C^2)(1+C^4) E14 + (1+C^2) y15,  z62 = C^4 y15,
//   U = (1+C) E61 + z62,  ls = (1+B)U + C z62,  rs = (1+A)U + C z62.
//
// Round 9: revert r8 (VGPR stayed 64 => allocator WANTS 64; sgr preload +
// 2-chain tapsum only added pressure: 84.6us). Back to the r7 structure
// (71.8us) with ONE change: the tap build is uniform scalar work repeated
// by every thread (~400 FMA per build; pass-1 did it twice plus ~190
// selects + 115 readfirstlanes ~= 5us of the 43.8us pass). Now pass-0
// block 0 writes all tap arrays (96 floats + 6 ints) to workspace; pass-1
// replaces both builds with ~12 broadcast float4 loads + readfirstlane.
// Freebie: pass-1 sg fetch trimmed to the epilogue's provable reach
// (s4 >= F0-600; deepest mattering E14 read is ~F0-480; r8 validated an
// equivalent trim) -- guard only, no register preload.
//
// Geometry: 64 rows x 4 chunks of 8000. SPAN=16384, HALO=8384 >= 8*E8
// (E8=8QB<=1048; QB<=131 since nUp+nDn=128). Pass1: F0=7*E8<=7336; epilogue
// worst-case reach 63*QB+DD+13 = 8382 <= 8384. PADF=1056 >= E8.

#define TLEN   32000
#define NROW   64
#define CHUNK  8000
#define NTH    1024
#define PT     16
#define PT4    (PT/4)
#define SPAN   (NTH*PT)        // 16384
#define HALO   (SPAN-CHUNK)    // 8384
#define PADF   1056            // front zero pad >= E8 max (1048)
#define BUF    (PADF+SPAN)     // 17440 floats = 69.76 KB per buffer

__device__ inline int swz4(int f) {        // f: float index, multiple of 4
  int B = f >> 2;
  B ^= (B >> 3) & 7;                       // permute 16B blocks in 8-groups
  return B << 2;
}

__device__ inline float sgprf(float x) {
  return __uint_as_float(__builtin_amdgcn_readfirstlane(__float_as_uint(x)));
}
__device__ inline int sgpri(int x) {
  return __builtin_amdgcn_readfirstlane(x);
}

struct Cf { int DU, DD, QB; float a[2], b[4], q[5], q2[9], q4[17], q8[33]; };

__device__ inline void build_from(float Lf, float pv, Cf& c) {
  const float p   = 0.1f + 0.8f * pv;
  const float nUp = Lf * p;
  const float nDn = Lf * (1.0f - p);
  c.DU = (int)ceilf(nUp);
  c.DD = (int)ceilf(nDn);
  const float fU = (float)c.DU - nUp;
  const float fD = (float)c.DD - nDn;
  const float GN  = -0.99f * 0.999f;        // NUT * VIB
  const float GB2 = -0.99f * 0.999f * 0.5f; // BRIDGE * VIB * 0.5
  c.a[0] = GN * (1.0f - fU);                // A: lag DU - i
  c.a[1] = GN * fU;
  const float w0 = 1.0f - fD, w1 = fD;
  c.b[0] = GB2 * (0.3f * w0);               // B: lag DD+2 - i
  c.b[1] = GB2 * (w0 + 0.3f * w1);
  c.b[2] = GB2 * (0.7f * w0 + w1);
  c.b[3] = GB2 * (0.7f * w1);
  c.QB = c.DU + c.DD + 2;                   // C: lag QB - i
#pragma unroll
  for (int m = 0; m < 5; ++m) c.q[m] = 0.f;
#pragma unroll
  for (int i = 0; i < 2; ++i)
#pragma unroll
    for (int j = 0; j < 4; ++j) c.q[i+j] = fmaf(c.a[i], c.b[j], c.q[i+j]);
#pragma unroll
  for (int m = 0; m < 9; ++m) c.q2[m] = 0.f;
#pragma unroll
  for (int i = 0; i < 5; ++i)
#pragma unroll
    for (int j = 0; j < 5; ++j) c.q2[i+j] = fmaf(c.q[i], c.q[j], c.q2[i+j]);
#pragma unroll
  for (int m = 0; m < 17; ++m) c.q4[m] = 0.f;
#pragma unroll
  for (int i = 0; i < 9; ++i)
#pragma unroll
    for (int j = 0; j < 9; ++j) c.q4[i+j] = fmaf(c.q2[i], c.q2[j], c.q4[i+j]);
#pragma unroll
  for (int m = 0; m < 33; ++m) c.q8[m] = 0.f;
#pragma unroll
  for (int i = 0; i < 17; ++i)
#pragma unroll
    for (int j = 0; j < 17; ++j) c.q8[i+j] = fmaf(c.q4[i], c.q4[j], c.q8[i+j]);
}

template<int NF4>
__device__ inline void ldwin(const float* b, int basef, float* v) {
#pragma unroll
  for (int i = 0; i < NF4; ++i) {
    float4 t4 = *(const float4*)&b[swz4(basef + 4*i)];
    v[4*i+0] = t4.x; v[4*i+1] = t4.y; v[4*i+2] = t4.z; v[4*i+3] = t4.w;
  }
}

// broadcast load NW floats from uniform global addr (16B-aligned) -> SGPRs
template<int NW>
__device__ inline void ldtaps(const float* g, float* dst) {
  float tmp[(NW + 3) & ~3];
#pragma unroll
  for (int i = 0; i < (NW + 3) / 4; ++i) {
    float4 v = ((const float4*)g)[i];
    tmp[4*i+0] = v.x; tmp[4*i+1] = v.y; tmp[4*i+2] = v.z; tmp[4*i+3] = v.w;
  }
#pragma unroll
  for (int m = 0; m < NW; ++m) dst[m] = sgprf(tmp[m]);
}

__device__ inline void stown(float* b, const int* wro, const float* v) {
#pragma unroll
  for (int k = 0; k < PT4; ++k)
    *(float4*)&b[wro[k]] = make_float4(v[4*k], v[4*k+1], v[4*k+2], v[4*k+3]);
}

__global__ __launch_bounds__(NTH, 4)
void gs_pass(const int* __restrict__ lenp, const float* __restrict__ pp,
             const float* __restrict__ exc,
             float* __restrict__ zg, float* __restrict__ sg,
             float* __restrict__ tapf, int* __restrict__ tapi,
             float* __restrict__ lout, float* __restrict__ rout, int pass)
{
  __shared__ __align__(16) float bufA[BUF];
  __shared__ __align__(16) float bufB[BUF];

  const int row   = blockIdx.x >> 2;
  const int chunk = blockIdx.x & 3;
  const int t0    = chunk * CHUNK;
  const int tid   = threadIdx.x;
  const int sbase = tid * PT;
  const size_t rb = (size_t)row * TLEN;
  const int steps = pass ? 7 : 8;

  // ---- taps for the evolve loop (W in SGPRs; only E8 else stays live) ----
  int E8;
  float W[33];
  if (pass == 0) {
    Cf c0; build_from((float)lenp[0], pp[0], c0);
#pragma unroll
    for (int m = 0; m < 33; ++m) W[m] = sgprf(c0.q8[m]);
    E8 = 8 * c0.QB;                       // multiple of 8, <= 1048
    if (blockIdx.x == 0 && tid == 0) {    // publish taps for pass 1
#pragma unroll
      for (int m = 0; m < 33; ++m) tapf[m] = c0.q8[m];
#pragma unroll
      for (int i = 0; i < 17; ++i) tapf[36 + i] = c0.q4[i];
      const int L2 = 2*c0.QB, L4 = 4*c0.QB, LQ = c0.QB,
                LB = c0.DD + 2, LA = c0.DU;
      const int L2e = (L2+3)&~3, sh2 = L2e-L2;
      const int LQe = (LQ+3)&~3, shq = LQe-LQ;
      const int LBe = (LB+3)&~3, shb = LBe-LB;
      const int LAe = (LA+3)&~3, sha = LAe-LA;
#pragma unroll
      for (int m = 0; m < 12; ++m)
        tapf[56 + m] = (m >= sh2 && m < sh2 + 9) ? c0.q2[m - sh2] : 0.f;
#pragma unroll
      for (int m = 0; m < 8; ++m)
        tapf[68 + m] = (m >= shq && m < shq + 5) ? c0.q[m - shq] : 0.f;
#pragma unroll
      for (int m = 0; m < 7; ++m)
        tapf[76 + m] = (m >= shb && m < shb + 4) ? c0.b[m - shb] : 0.f;
      tapf[83] = 0.f;
#pragma unroll
      for (int m = 0; m < 5; ++m)
        tapf[84 + m] = (m >= sha && m < sha + 2) ? c0.a[m - sha] : 0.f;
      tapf[89] = tapf[90] = tapf[91] = 0.f;
      tapi[0] = E8; tapi[1] = L2e; tapi[2] = L4;
      tapi[3] = LQe; tapi[4] = LBe; tapi[5] = LAe;
    }
  } else {
    ldtaps<33>(tapf, W);
    E8 = sgpri(tapi[0]);
  }

  // ---- precomputed swizzled offsets ----
  int rdo[12], wro[PT4];
#pragma unroll
  for (int i = 0; i < 12; ++i) rdo[i] = swz4(PADF + sbase - E8 + 4*i);
#pragma unroll
  for (int k = 0; k < PT4; ++k) wro[k] = swz4(PADF + sbase + 4*k);

  // ---- staging ----
  const float4 f4z = make_float4(0.f, 0.f, 0.f, 0.f);
  if (tid * 4 < PADF) {                                // zero front pads
    *(float4*)&bufA[swz4(tid*4)] = f4z;
    *(float4*)&bufB[swz4(tid*4)] = f4z;
  }
  if (chunk == 0) {                                    // true zeros at t<0
    for (int s4 = tid*4; s4 < HALO; s4 += NTH*4)
      *(float4*)&bufB[swz4(PADF + s4)] = f4z;
  }
#pragma unroll
  for (int k = 0; k < 4; ++k) {                        // coalesced state load
    int s4 = tid*4 + k*(NTH*4);
    int t  = t0 - HALO + s4;
    float4 v = f4z;
    if (t >= 0) {
      if (pass == 0) {
        float4 e = *(const float4*)&exc[rb + t];
        v = make_float4(0.5f*e.x, 0.5f*e.y, 0.5f*e.z, 0.5f*e.w);
      } else {
        v = *(const float4*)&zg[rb + t];
      }
    }
    *(float4*)&bufA[swz4(PADF + s4)] = v;
  }
  __syncthreads();

  float* cur = bufA;
  float* nxt = bufB;

  // own samples + partial sum
  float z[PT], acc[PT];
#pragma unroll
  for (int k = 0; k < PT4; ++k) {
    float4 t4 = *(const float4*)&cur[wro[k]];
    z[4*k+0] = t4.x; z[4*k+1] = t4.y; z[4*k+2] = t4.z; z[4*k+3] = t4.w;
  }
#pragma unroll
  for (int j = 0; j < PT; ++j) acc[j] = 0.f;

  // ---- evolve (z updated in place; acc += old z first) ----
  for (int s = 0; s < steps; ++s) {
    const int limit = (chunk == 0) ? HALO : (s + 1) * E8;
    const bool alive = (sbase + PT > limit);
    if (alive) {
      float v[48];                         // PT + 32 floats, 16B-aligned
#pragma unroll
      for (int i = 0; i < 12; ++i) {
        float4 t4 = *(const float4*)&cur[rdo[i]];
        v[4*i+0] = t4.x; v[4*i+1] = t4.y; v[4*i+2] = t4.z; v[4*i+3] = t4.w;
      }
#pragma unroll
      for (int j = 0; j < PT; ++j) acc[j] += z[j];
#pragma unroll
      for (int j = 0; j < PT; ++j) {
        float sv = W[0] * v[j];
#pragma unroll
        for (int m = 1; m < 33; ++m) sv = fmaf(W[m], v[j+m], sv);
        z[j] = sv;
      }
      stown(nxt, wro, z);
    }
    __syncthreads();
    float* tp = cur; cur = nxt; nxt = tp;
  }

  if (pass == 0) {
    // cur = y8, stage acc; writeback own region.
    stown(nxt, wro, acc);
    __syncthreads();
#pragma unroll
    for (int k = 0; k < 2; ++k) {
      int s4 = HALO + tid*4 + k*(NTH*4);
      if (s4 < SPAN) {
        int t = t0 + s4 - HALO;
        *(float4*)&zg[rb + t] = *(const float4*)&cur[swz4(PADF + s4)];
        *(float4*)&sg[rb + t] = *(const float4*)&nxt[swz4(PADF + s4)];
      }
    }
    return;
  }

  // ================= pass 1 epilogue (cur = y15, z = y15 own) ===========
  const int F0 = 7 * E8;
  // P0: E14 = acc + sg (L3-hot from pass 0) into nxt, trimmed to the
  // epilogue's reach (deepest mattering E14 read ~= F0-480).
  stown(nxt, wro, acc);
  __syncthreads();
#pragma unroll
  for (int k = 0; k < 4; ++k) {
    int s4 = tid*4 + k*(NTH*4);
    int t  = t0 - HALO + s4;
    float4 sv = f4z;
    if (t >= 0 && (chunk == 0 || s4 >= F0 - 600))
      sv = *(const float4*)&sg[rb + t];
    int o = swz4(PADF + s4);
    float4 a4 = *(const float4*)&nxt[o];
    *(float4*)&nxt[o] = make_float4(a4.x + sv.x, a4.y + sv.y,
                                    a4.z + sv.z, a4.w + sv.w);
  }
  __syncthreads();

  // Epilogue taps: broadcast loads (keeps the evolve loop lean; the asm
  // barrier stops LICM from hoisting these above the evolve loop).
  asm volatile("" ::: "memory");
  float q4f[17], T2[12], TQ[8], TB[7], TA[5];
  ldtaps<17>(tapf + 36, q4f);
  ldtaps<12>(tapf + 56, T2);
  ldtaps<8>(tapf + 68, TQ);
  ldtaps<7>(tapf + 76, TB);
  ldtaps<5>(tapf + 84, TA);
  const int L2e = sgpri(tapi[1]), L4  = sgpri(tapi[2]), LQe = sgpri(tapi[3]),
            LBe = sgpri(tapi[4]), LAe = sgpri(tapi[5]);

  const bool ae = (chunk == 0) || (sbase + PT > F0);

  // Ph-A: H1 = (1+C^2)E14 ; Y2 = (1+C^2)y15 ; z62 = C^4 y15
  float H1[PT], Y2[PT], z62[PT];
  if (ae) {
    float e0[PT];
#pragma unroll
    for (int k = 0; k < PT4; ++k) {
      float4 t4 = *(const float4*)&nxt[wro[k]];
      e0[4*k+0] = t4.x; e0[4*k+1] = t4.y; e0[4*k+2] = t4.z; e0[4*k+3] = t4.w;
    }
    float w[28];
    ldwin<7>(nxt, PADF + sbase - L2e, w);
#pragma unroll
    for (int j = 0; j < PT; ++j) {
      float sv = e0[j];
#pragma unroll
      for (int m = 0; m < 12; ++m) sv = fmaf(T2[m], w[j+m], sv);
      H1[j] = sv;
    }
    ldwin<7>(cur, PADF + sbase - L2e, w);
#pragma unroll
    for (int j = 0; j < PT; ++j) {
      float sv = z[j];
#pragma unroll
      for (int m = 0; m < 12; ++m) sv = fmaf(T2[m], w[j+m], sv);
      Y2[j] = sv;
    }
    float w4[32];
    ldwin<8>(cur, PADF + sbase - L4, w4);    // L4 = 4QB, multiple of 4
#pragma unroll
    for (int j = 0; j < PT; ++j) {
      float sv = q4f[0] * w4[j];
#pragma unroll
      for (int m = 1; m < 17; ++m) sv = fmaf(q4f[m], w4[j+m], sv);
      z62[j] = sv;
    }
  }
  __syncthreads();
  if (ae) { stown(nxt, wro, H1); stown(cur, wro, z62); }
  __syncthreads();

  // Ph-B: E61 = H1 + C^4 H1 + Y2
  float E61[PT];
  if (ae) {
    float w4[32];
    ldwin<8>(nxt, PADF + sbase - L4, w4);
#pragma unroll
    for (int j = 0; j < PT; ++j) {
      float sv = H1[j] + Y2[j];
#pragma unroll
      for (int m = 0; m < 17; ++m) sv = fmaf(q4f[m], w4[j+m], sv);
      E61[j] = sv;
    }
  }
  __syncthreads();
  if (ae) stown(nxt, wro, E61);
  __syncthreads();

  // Ph-C: U = E61 + C E61 + z62 ; V = C z62
  float U[PT], V[PT];
  if (ae) {
    float w[24];
    ldwin<6>(nxt, PADF + sbase - LQe, w);
#pragma unroll
    for (int j = 0; j < PT; ++j) {
      float sv = E61[j] + z62[j];
#pragma unroll
      for (int m = 0; m < 8; ++m) sv = fmaf(TQ[m], w[j+m], sv);
      U[j] = sv;
    }
    ldwin<6>(cur, PADF + sbase - LQe, w);
#pragma unroll
    for (int j = 0; j < PT; ++j) {
      float sv = TQ[0] * w[j];
#pragma unroll
      for (int m = 1; m < 8; ++m) sv = fmaf(TQ[m], w[j+m], sv);
      V[j] = sv;
    }
  }
  __syncthreads();
  if (ae) stown(nxt, wro, U);
  __syncthreads();

  // Ph-D: s0 = U+V (into V); ls = s0 + B U; rs = s0 + A U
  float LSv[PT], RSv[PT];
  if (ae) {
#pragma unroll
    for (int j = 0; j < PT; ++j) V[j] += U[j];
    {
      float wb[24];
      ldwin<6>(nxt, PADF + sbase - LBe, wb);
#pragma unroll
      for (int j = 0; j < PT; ++j) {
        float sv = V[j];
#pragma unroll
        for (int m = 0; m < 7; ++m) sv = fmaf(TB[m], wb[j+m], sv);
        LSv[j] = sv;
      }
    }
    {
      float wa[20];
      ldwin<5>(nxt, PADF + sbase - LAe, wa);
#pragma unroll
      for (int j = 0; j < PT; ++j) {
        float sv = V[j];
#pragma unroll
        for (int m = 0; m < 5; ++m) sv = fmaf(TA[m], wa[j+m], sv);
        RSv[j] = sv;
      }
    }
  }
  __syncthreads();
  if (ae) { stown(cur, wro, LSv); stown(nxt, wro, RSv); }
  __syncthreads();

  // coalesced output store
#pragma unroll
  for (int k = 0; k < 2; ++k) {
    int s4 = HALO + tid*4 + k*(NTH*4);
    if (s4 < SPAN) {
      int t = t0 + s4 - HALO;
      *(float4*)&lout[rb + t] = *(const float4*)&cur[swz4(PADF + s4)];
      *(float4*)&rout[rb + t] = *(const float4*)&nxt[swz4(PADF + s4)];
    }
  }
}

extern "C" void kernel_launch(void* const* d_in, const int* in_sizes, int n_in,
                              void* d_out, int out_size, void* d_ws, size_t ws_size,
                              hipStream_t stream) {
  (void)in_sizes; (void)n_in; (void)out_size; (void)ws_size;

  const int*   lenp = (const int*)d_in[0];
  const float* pp   = (const float*)d_in[1];
  const float* exc  = (const float*)d_in[2];

  float* lout = (float*)d_out;                  // ls: 64*32000 f32
  float* rout = lout + (size_t)NROW * TLEN;     // rs

  float* zg   = (float*)d_ws;                   // state y8
  float* sg   = zg + (size_t)NROW * TLEN;       // partial sum y0..y7
  float* tapf = sg + (size_t)NROW * TLEN;       // 96 floats of taps
  int*   tapi = (int*)(tapf + 96);              // 6 ints of geometry

  dim3 grid(NROW * 4);
  gs_pass<<<grid, dim3(NTH), 0, stream>>>(lenp, pp, exc, zg, sg, tapf, tapi,
                                          lout, rout, 0);
  gs_pass<<<grid, dim3(NTH), 0, stream>>>(lenp, pp, exc, zg, sg, tapf, tapi,
                                          lout, rout, 1);
}

// Round 3
// 76.690 us; speedup vs baseline: 1.1031x; 1.0702x over previous
//
#include <hip/hip_runtime.h>

// Guitar string (Karplus-Strong waveguide), MI355X gfx950.
//
// LTI reformulation (validated rounds 2-6): A (l->r, 2 taps) and B (r->l,
// 4 taps) commute; both parities evolve by C = A*B (5 taps, lag QB=DU+DD+2).
// Evolve y_m = (C^8)^m (0.5 e) (33 taps, lag 8QB); E14 = sum_{0..14} y_m;
//   E61 = (1+C^2)(1+C^4) E14 + (1+C^2) y15,  z62 = C^4 y15,
//   U = (1+C) E61 + z62,  ls = (1+B)U + C z62,  rs = (1+A)U + C z62.
//
// Round 10: r9's in-kernel tap publish kept the whole Cf struct live across
// staging inside a 64-VGPR budget -> per-thread scratch spill (WRITE_SIZE
// 18->96 MB, pass-0 28->62us; spill code in shared paths hurt pass-1 too).
// Fix: build_from moves to a separate trivial kernel (gs_taps, 1 block;
// ~2us). gs_pass never instantiates Cf: both passes fetch taps with ~12
// broadcast float4 loads + readfirstlane (kills the ~400-FMA uniform build
// r0 paid in EVERY thread of BOTH passes). Everything else is bit-identical
// to the 71.8us r0 structure; pass-1 sg fetch keeps the validated reach
// trim (s4 >= F0-600, chunk != 0).
//
// Geometry: 64 rows x 4 chunks of 8000. SPAN=16384, HALO=8384 >= 8*E8
// (E8=8QB<=1048; QB<=131 since nUp+nDn=128). Pass1: F0=7*E8<=7336; epilogue
// worst-case reach 63*QB+DD+13 = 8382 <= 8384. PADF=1056 >= E8.

#define TLEN   32000
#define NROW   64
#define CHUNK  8000
#define NTH    1024
#define PT     16
#define PT4    (PT/4)
#define SPAN   (NTH*PT)        // 16384
#define HALO   (SPAN-CHUNK)    // 8384
#define PADF   1056            // front zero pad >= E8 max (1048)
#define BUF    (PADF+SPAN)     // 17440 floats = 69.76 KB per buffer

__device__ inline int swz4(int f) {        // f: float index, multiple of 4
  int B = f >> 2;
  B ^= (B >> 3) & 7;                       // permute 16B blocks in 8-groups
  return B << 2;
}

__device__ inline float sgprf(float x) {
  return __uint_as_float(__builtin_amdgcn_readfirstlane(__float_as_uint(x)));
}
__device__ inline int sgpri(int x) {
  return __builtin_amdgcn_readfirstlane(x);
}

struct Cf { int DU, DD, QB; float a[2], b[4], q[5], q2[9], q4[17], q8[33]; };

__device__ inline void build_from(float Lf, float pv, Cf& c) {
  const float p   = 0.1f + 0.8f * pv;
  const float nUp = Lf * p;
  const float nDn = Lf * (1.0f - p);
  c.DU = (int)ceilf(nUp);
  c.DD = (int)ceilf(nDn);
  const float fU = (float)c.DU - nUp;
  const float fD = (float)c.DD - nDn;
  const float GN  = -0.99f * 0.999f;        // NUT * VIB
  const float GB2 = -0.99f * 0.999f * 0.5f; // BRIDGE * VIB * 0.5
  c.a[0] = GN * (1.0f - fU);                // A: lag DU - i
  c.a[1] = GN * fU;
  const float w0 = 1.0f - fD, w1 = fD;
  c.b[0] = GB2 * (0.3f * w0);               // B: lag DD+2 - i
  c.b[1] = GB2 * (w0 + 0.3f * w1);
  c.b[2] = GB2 * (0.7f * w0 + w1);
  c.b[3] = GB2 * (0.7f * w1);
  c.QB = c.DU + c.DD + 2;                   // C: lag QB - i
#pragma unroll
  for (int m = 0; m < 5; ++m) c.q[m] = 0.f;
#pragma unroll
  for (int i = 0; i < 2; ++i)
#pragma unroll
    for (int j = 0; j < 4; ++j) c.q[i+j] = fmaf(c.a[i], c.b[j], c.q[i+j]);
#pragma unroll
  for (int m = 0; m < 9; ++m) c.q2[m] = 0.f;
#pragma unroll
  for (int i = 0; i < 5; ++i)
#pragma unroll
    for (int j = 0; j < 5; ++j) c.q2[i+j] = fmaf(c.q[i], c.q[j], c.q2[i+j]);
#pragma unroll
  for (int m = 0; m < 17; ++m) c.q4[m] = 0.f;
#pragma unroll
  for (int i = 0; i < 9; ++i)
#pragma unroll
    for (int j = 0; j < 9; ++j) c.q4[i+j] = fmaf(c.q2[i], c.q2[j], c.q4[i+j]);
#pragma unroll
  for (int m = 0; m < 33; ++m) c.q8[m] = 0.f;
#pragma unroll
  for (int i = 0; i < 17; ++i)
#pragma unroll
    for (int j = 0; j < 17; ++j) c.q8[i+j] = fmaf(c.q4[i], c.q4[j], c.q8[i+j]);
}

// ---- tiny setup kernel: publish all tap arrays + geometry once ----
__global__ void gs_taps(const int* __restrict__ lenp,
                        const float* __restrict__ pp,
                        float* __restrict__ tapf, int* __restrict__ tapi)
{
  if (threadIdx.x != 0) return;
  Cf c; build_from((float)lenp[0], pp[0], c);
#pragma unroll
  for (int m = 0; m < 96; ++m) tapf[m] = 0.f;
#pragma unroll
  for (int m = 0; m < 33; ++m) tapf[m] = c.q8[m];
#pragma unroll
  for (int i = 0; i < 17; ++i) tapf[36 + i] = c.q4[i];
  const int L2 = 2*c.QB, L4 = 4*c.QB, LQ = c.QB, LB = c.DD + 2, LA = c.DU;
  const int L2e = (L2+3)&~3, sh2 = L2e-L2;
  const int LQe = (LQ+3)&~3, shq = LQe-LQ;
  const int LBe = (LB+3)&~3, shb = LBe-LB;
  const int LAe = (LA+3)&~3, sha = LAe-LA;
#pragma unroll
  for (int i = 0; i < 9; ++i) tapf[56 + sh2 + i] = c.q2[i];
#pragma unroll
  for (int i = 0; i < 5; ++i) tapf[68 + shq + i] = c.q[i];
#pragma unroll
  for (int i = 0; i < 4; ++i) tapf[76 + shb + i] = c.b[i];
#pragma unroll
  for (int i = 0; i < 2; ++i) tapf[84 + sha + i] = c.a[i];
  tapi[0] = 8 * c.QB; tapi[1] = L2e; tapi[2] = L4;
  tapi[3] = LQe; tapi[4] = LBe; tapi[5] = LAe;
}

template<int NF4>
__device__ inline void ldwin(const float* b, int basef, float* v) {
#pragma unroll
  for (int i = 0; i < NF4; ++i) {
    float4 t4 = *(const float4*)&b[swz4(basef + 4*i)];
    v[4*i+0] = t4.x; v[4*i+1] = t4.y; v[4*i+2] = t4.z; v[4*i+3] = t4.w;
  }
}

// broadcast load NW floats from uniform global addr (16B-aligned) -> SGPRs
template<int NW>
__device__ inline void ldtaps(const float* g, float* dst) {
  float tmp[(NW + 3) & ~3];
#pragma unroll
  for (int i = 0; i < (NW + 3) / 4; ++i) {
    float4 v = ((const float4*)g)[i];
    tmp[4*i+0] = v.x; tmp[4*i+1] = v.y; tmp[4*i+2] = v.z; tmp[4*i+3] = v.w;
  }
#pragma unroll
  for (int m = 0; m < NW; ++m) dst[m] = sgprf(tmp[m]);
}

__device__ inline void stown(float* b, const int* wro, const float* v) {
#pragma unroll
  for (int k = 0; k < PT4; ++k)
    *(float4*)&b[wro[k]] = make_float4(v[4*k], v[4*k+1], v[4*k+2], v[4*k+3]);
}

__global__ __launch_bounds__(NTH, 4)
void gs_pass(const float* __restrict__ exc,
             float* __restrict__ zg, float* __restrict__ sg,
             const float* __restrict__ tapf, const int* __restrict__ tapi,
             float* __restrict__ lout, float* __restrict__ rout, int pass)
{
  __shared__ __align__(16) float bufA[BUF];
  __shared__ __align__(16) float bufB[BUF];

  const int row   = blockIdx.x >> 2;
  const int chunk = blockIdx.x & 3;
  const int t0    = chunk * CHUNK;
  const int tid   = threadIdx.x;
  const int sbase = tid * PT;
  const size_t rb = (size_t)row * TLEN;
  const int steps = pass ? 7 : 8;

  // ---- taps for the evolve loop: broadcast loads, no build ----
  float W[33];
  ldtaps<33>(tapf, W);
  const int E8 = sgpri(tapi[0]);          // multiple of 8, <= 1048

  // ---- precomputed swizzled offsets ----
  int rdo[12], wro[PT4];
#pragma unroll
  for (int i = 0; i < 12; ++i) rdo[i] = swz4(PADF + sbase - E8 + 4*i);
#pragma unroll
  for (int k = 0; k < PT4; ++k) wro[k] = swz4(PADF + sbase + 4*k);

  // ---- staging ----
  const float4 f4z = make_float4(0.f, 0.f, 0.f, 0.f);
  if (tid * 4 < PADF) {                                // zero front pads
    *(float4*)&bufA[swz4(tid*4)] = f4z;
    *(float4*)&bufB[swz4(tid*4)] = f4z;
  }
  if (chunk == 0) {                                    // true zeros at t<0
    for (int s4 = tid*4; s4 < HALO; s4 += NTH*4)
      *(float4*)&bufB[swz4(PADF + s4)] = f4z;
  }
#pragma unroll
  for (int k = 0; k < 4; ++k) {                        // coalesced state load
    int s4 = tid*4 + k*(NTH*4);
    int t  = t0 - HALO + s4;
    float4 v = f4z;
    if (t >= 0) {
      if (pass == 0) {
        float4 e = *(const float4*)&exc[rb + t];
        v = make_float4(0.5f*e.x, 0.5f*e.y, 0.5f*e.z, 0.5f*e.w);
      } else {
        v = *(const float4*)&zg[rb + t];
      }
    }
    *(float4*)&bufA[swz4(PADF + s4)] = v;
  }
  __syncthreads();

  float* cur = bufA;
  float* nxt = bufB;

  // own samples + partial sum
  float z[PT], acc[PT];
#pragma unroll
  for (int k = 0; k < PT4; ++k) {
    float4 t4 = *(const float4*)&cur[wro[k]];
    z[4*k+0] = t4.x; z[4*k+1] = t4.y; z[4*k+2] = t4.z; z[4*k+3] = t4.w;
  }
#pragma unroll
  for (int j = 0; j < PT; ++j) acc[j] = 0.f;

  // ---- evolve (z updated in place; acc += old z first) ----
  for (int s = 0; s < steps; ++s) {
    const int limit = (chunk == 0) ? HALO : (s + 1) * E8;
    const bool alive = (sbase + PT > limit);
    if (alive) {
      float v[48];                         // PT + 32 floats, 16B-aligned
#pragma unroll
      for (int i = 0; i < 12; ++i) {
        float4 t4 = *(const float4*)&cur[rdo[i]];
        v[4*i+0] = t4.x; v[4*i+1] = t4.y; v[4*i+2] = t4.z; v[4*i+3] = t4.w;
      }
#pragma unroll
      for (int j = 0; j < PT; ++j) acc[j] += z[j];
#pragma unroll
      for (int j = 0; j < PT; ++j) {
        float sv = W[0] * v[j];
#pragma unroll
        for (int m = 1; m < 33; ++m) sv = fmaf(W[m], v[j+m], sv);
        z[j] = sv;
      }
      stown(nxt, wro, z);
    }
    __syncthreads();
    float* tp = cur; cur = nxt; nxt = tp;
  }

  if (pass == 0) {
    // cur = y8, stage acc; writeback own region.
    stown(nxt, wro, acc);
    __syncthreads();
#pragma unroll
    for (int k = 0; k < 2; ++k) {
      int s4 = HALO + tid*4 + k*(NTH*4);
      if (s4 < SPAN) {
        int t = t0 + s4 - HALO;
        *(float4*)&zg[rb + t] = *(const float4*)&cur[swz4(PADF + s4)];
        *(float4*)&sg[rb + t] = *(const float4*)&nxt[swz4(PADF + s4)];
      }
    }
    return;
  }

  // ================= pass 1 epilogue (cur = y15, z = y15 own) ===========
  const int F0 = 7 * E8;
  // P0: E14 = acc + sg (L3-hot from pass 0) into nxt, trimmed to the
  // epilogue's reach (deepest mattering E14 read ~= F0-480).
  stown(nxt, wro, acc);
  __syncthreads();
#pragma unroll
  for (int k = 0; k < 4; ++k) {
    int s4 = tid*4 + k*(NTH*4);
    int t  = t0 - HALO + s4;
    float4 sv = f4z;
    if (t >= 0 && (chunk == 0 || s4 >= F0 - 600))
      sv = *(const float4*)&sg[rb + t];
    int o = swz4(PADF + s4);
    float4 a4 = *(const float4*)&nxt[o];
    *(float4*)&nxt[o] = make_float4(a4.x + sv.x, a4.y + sv.y,
                                    a4.z + sv.z, a4.w + sv.w);
  }
  __syncthreads();

  // Epilogue taps: broadcast loads (asm barrier stops LICM hoisting them
  // above the evolve loop, which would lengthen SGPR liveness).
  asm volatile("" ::: "memory");
  float q4f[17], T2[12], TQ[8], TB[7], TA[5];
  ldtaps<17>(tapf + 36, q4f);
  ldtaps<12>(tapf + 56, T2);
  ldtaps<8>(tapf + 68, TQ);
  ldtaps<7>(tapf + 76, TB);
  ldtaps<5>(tapf + 84, TA);
  const int L2e = sgpri(tapi[1]), L4  = sgpri(tapi[2]), LQe = sgpri(tapi[3]),
            LBe = sgpri(tapi[4]), LAe = sgpri(tapi[5]);

  const bool ae = (chunk == 0) || (sbase + PT > F0);

  // Ph-A: H1 = (1+C^2)E14 ; Y2 = (1+C^2)y15 ; z62 = C^4 y15
  float H1[PT], Y2[PT], z62[PT];
  if (ae) {
    float e0[PT];
#pragma unroll
    for (int k = 0; k < PT4; ++k) {
      float4 t4 = *(const float4*)&nxt[wro[k]];
      e0[4*k+0] = t4.x; e0[4*k+1] = t4.y; e0[4*k+2] = t4.z; e0[4*k+3] = t4.w;
    }
    float w[28];
    ldwin<7>(nxt, PADF + sbase - L2e, w);
#pragma unroll
    for (int j = 0; j < PT; ++j) {
      float sv = e0[j];
#pragma unroll
      for (int m = 0; m < 12; ++m) sv = fmaf(T2[m], w[j+m], sv);
      H1[j] = sv;
    }
    ldwin<7>(cur, PADF + sbase - L2e, w);
#pragma unroll
    for (int j = 0; j < PT; ++j) {
      float sv = z[j];
#pragma unroll
      for (int m = 0; m < 12; ++m) sv = fmaf(T2[m], w[j+m], sv);
      Y2[j] = sv;
    }
    float w4[32];
    ldwin<8>(cur, PADF + sbase - L4, w4);    // L4 = 4QB, multiple of 4
#pragma unroll
    for (int j = 0; j < PT; ++j) {
      float sv = q4f[0] * w4[j];
#pragma unroll
      for (int m = 1; m < 17; ++m) sv = fmaf(q4f[m], w4[j+m], sv);
      z62[j] = sv;
    }
  }
  __syncthreads();
  if (ae) { stown(nxt, wro, H1); stown(cur, wro, z62); }
  __syncthreads();

  // Ph-B: E61 = H1 + C^4 H1 + Y2
  float E61[PT];
  if (ae) {
    float w4[32];
    ldwin<8>(nxt, PADF + sbase - L4, w4);
#pragma unroll
    for (int j = 0; j < PT; ++j) {
      float sv = H1[j] + Y2[j];
#pragma unroll
      for (int m = 0; m < 17; ++m) sv = fmaf(q4f[m], w4[j+m], sv);
      E61[j] = sv;
    }
  }
  __syncthreads();
  if (ae) stown(nxt, wro, E61);
  __syncthreads();

  // Ph-C: U = E61 + C E61 + z62 ; V = C z62
  float U[PT], V[PT];
  if (ae) {
    float w[24];
    ldwin<6>(nxt, PADF + sbase - LQe, w);
#pragma unroll
    for (int j = 0; j < PT; ++j) {
      float sv = E61[j] + z62[j];
#pragma unroll
      for (int m = 0; m < 8; ++m) sv = fmaf(TQ[m], w[j+m], sv);
      U[j] = sv;
    }
    ldwin<6>(cur, PADF + sbase - LQe, w);
#pragma unroll
    for (int j = 0; j < PT; ++j) {
      float sv = TQ[0] * w[j];
#pragma unroll
      for (int m = 1; m < 8; ++m) sv = fmaf(TQ[m], w[j+m], sv);
      V[j] = sv;
    }
  }
  __syncthreads();
  if (ae) stown(nxt, wro, U);
  __syncthreads();

  // Ph-D: s0 = U+V (into V); ls = s0 + B U; rs = s0 + A U
  float LSv[PT], RSv[PT];
  if (ae) {
#pragma unroll
    for (int j = 0; j < PT; ++j) V[j] += U[j];
    {
      float wb[24];
      ldwin<6>(nxt, PADF + sbase - LBe, wb);
#pragma unroll
      for (int j = 0; j < PT; ++j) {
        float sv = V[j];
#pragma unroll
        for (int m = 0; m < 7; ++m) sv = fmaf(TB[m], wb[j+m], sv);
        LSv[j] = sv;
      }
    }
    {
      float wa[20];
      ldwin<5>(nxt, PADF + sbase - LAe, wa);
#pragma unroll
      for (int j = 0; j < PT; ++j) {
        float sv = V[j];
#pragma unroll
        for (int m = 0; m < 5; ++m) sv = fmaf(TA[m], wa[j+m], sv);
        RSv[j] = sv;
      }
    }
  }
  __syncthreads();
  if (ae) { stown(cur, wro, LSv); stown(nxt, wro, RSv); }
  __syncthreads();

  // coalesced output store
#pragma unroll
  for (int k = 0; k < 2; ++k) {
    int s4 = HALO + tid*4 + k*(NTH*4);
    if (s4 < SPAN) {
      int t = t0 + s4 - HALO;
      *(float4*)&lout[rb + t] = *(const float4*)&cur[swz4(PADF + s4)];
      *(float4*)&rout[rb + t] = *(const float4*)&nxt[swz4(PADF + s4)];
    }
  }
}

extern "C" void kernel_launch(void* const* d_in, const int* in_sizes, int n_in,
                              void* d_out, int out_size, void* d_ws, size_t ws_size,
                              hipStream_t stream) {
  (void)in_sizes; (void)n_in; (void)out_size; (void)ws_size;

  const int*   lenp = (const int*)d_in[0];
  const float* pp   = (const float*)d_in[1];
  const float* exc  = (const float*)d_in[2];

  float* lout = (float*)d_out;                  // ls: 64*32000 f32
  float* rout = lout + (size_t)NROW * TLEN;     // rs

  float* zg   = (float*)d_ws;                   // state y8
  float* sg   = zg + (size_t)NROW * TLEN;       // partial sum y0..y7
  float* tapf = sg + (size_t)NROW * TLEN;       // 96 floats of taps
  int*   tapi = (int*)(tapf + 96);              // 6 ints of geometry

  dim3 grid(NROW * 4);
  gs_taps<<<dim3(1), dim3(64), 0, stream>>>(lenp, pp, tapf, tapi);
  gs_pass<<<grid, dim3(NTH), 0, stream>>>(exc, zg, sg, tapf, tapi,
                                          lout, rout, 0);
  gs_pass<<<grid, dim3(NTH), 0, stream>>>(exc, zg, sg, tapf, tapi,
                                          lout, rout, 1);
}